// Round 6
// baseline (553.558 us; speedup 1.0000x reference)
//
#include <hip/hip_runtime.h>
#include <hip/hip_bf16.h>
#include <cmath>
#include <cstdint>

// Problem constants
#define SEQ    2048
#define HID    3584
#define NH     28
#define NKV    4
#define HD     128
#define KOFF   3584
#define VOFF   4096
#define QSCALE 0.08838834764831845f   // 1/sqrt(128)
#define LOG2E  1.4426950408889634f
#define NKT    56                     // K-tiles of 64 over HID=3584

typedef __attribute__((ext_vector_type(8))) short bf16x8;
typedef __attribute__((ext_vector_type(4))) float f32x4;

__device__ inline short f2bf(float f){
    union { float f; uint32_t u; } c; c.f = f;
    uint32_t u = c.u;
    uint32_t r = (u + 0x7fffu + ((u >> 16) & 1u)) >> 16;
    return (short)r;
}

// async global->LDS, 16B per lane; LDS dest = wave-uniform base + lane*16
__device__ __forceinline__ void gl_lds16(const short* g, short* l) {
    __builtin_amdgcn_global_load_lds(
        (const __attribute__((address_space(1))) void*)g,
        (__attribute__((address_space(3))) void*)l,
        16, 0, 0);
}

#define WAIT_VM0  asm volatile("s_waitcnt vmcnt(0)" ::: "memory")
#define WAIT_LGKM asm volatile("s_waitcnt lgkmcnt(0)" ::: "memory")
#define BARRIER   asm volatile("s_barrier" ::: "memory")

// ---------------------------------------------------------------- fused convert (5 segments, compile-time bounds)
// seg n8 sizes: hid 917504 | Wq 1605632 | Wk 229376 | Wv 229376 | Wo 1605632
#define C0 917504
#define C1 2523136
#define C2 2752512
#define C3 2981888
#define C4 4587520
__global__ void cvt_all(const float* __restrict__ hid, const float* __restrict__ wq,
                        const float* __restrict__ wk,  const float* __restrict__ wv,
                        const float* __restrict__ wo,
                        short* __restrict__ hid_d, short* __restrict__ wqkv_d,
                        short* __restrict__ wo_d)
{
    int i = blockIdx.x * blockDim.x + threadIdx.x;
    if (i >= C4) return;
    const float* src; short* dst; size_t j;
    if      (i < C0) { src = hid; dst = hid_d;                        j = i; }
    else if (i < C1) { src = wq;  dst = wqkv_d;                       j = i - C0; }
    else if (i < C2) { src = wk;  dst = wqkv_d + (size_t)3584*HID;    j = i - C1; }
    else if (i < C3) { src = wv;  dst = wqkv_d + (size_t)4096*HID;    j = i - C2; }
    else             { src = wo;  dst = wo_d;                         j = i - C3; }
    float4 a = ((const float4*)src)[2*j];
    float4 b = ((const float4*)src)[2*j+1];
    bf16x8 o;
    o[0]=f2bf(a.x); o[1]=f2bf(a.y); o[2]=f2bf(a.z); o[3]=f2bf(a.w);
    o[4]=f2bf(b.x); o[5]=f2bf(b.y); o[6]=f2bf(b.z); o[7]=f2bf(b.w);
    ((bf16x8*)dst)[j] = o;
}

// ---------------------------------------------------------------- 256x256 8-phase GEMM core (verified R1)
__device__ __forceinline__ void gemm256_core(
    const short* __restrict__ A, const short* __restrict__ Bw,
    const int m0, const int n0, const int (&brow)[4],
    f32x4 (&acc)[8][4],
    short (&ldsA)[2][256*64], short (&ldsB)[2][256*64])
{
    const int tid  = threadIdx.x;
    const int wave = tid >> 6, lane = tid & 63;
    const int lq   = lane >> 4, l16 = lane & 15;
    const int wr   = wave >> 2;
    const int lrow = lane >> 3;                  // 0..7
    const int gchk = ((lane & 7) ^ lrow) << 3;   // swizzled 16B-chunk offset (shorts)

    const short* Ab = &A [(size_t)(m0 + wave*8 + lrow)*HID + gchk];
    const short* Bb = &Bw[(size_t)(n0 + wave*8 + lrow)*HID + gchk];

    auto issueA = [&](int k0, int b) {
        #pragma unroll
        for (int j = 0; j < 4; j++)
            gl_lds16(Ab + (size_t)j*64*HID + k0, &ldsA[b][(j*64 + wave*8)*64]);
    };
    auto issueB = [&](int k0, int b) {
        #pragma unroll
        for (int j = 0; j < 4; j++)
            gl_lds16(Bb + (size_t)j*64*HID + k0, &ldsB[b][(j*64 + wave*8)*64]);
    };

    #pragma unroll
    for (int i = 0; i < 8; i++)
        #pragma unroll
        for (int j = 0; j < 4; j++) acc[i][j] = (f32x4){0.f,0.f,0.f,0.f};

    bf16x8 bfr[4][2];    // all B-fragments for the tile, read once in phase 0

    auto readA = [&](int p, int qd, bf16x8 (&af)[2][2]) {
        #pragma unroll
        for (int iq = 0; iq < 2; iq++)
            #pragma unroll
            for (int ks = 0; ks < 2; ks++)
                af[iq][ks] = *(const bf16x8*)&ldsA[p][(wr*128 + (qd*2+iq)*16 + l16)*64
                                                      + (((ks*4 + lq) ^ (l16 & 7)) << 3)];
    };
    auto mfma16 = [&](int qd, const bf16x8 (&af)[2][2]) {
        #pragma unroll
        for (int ks = 0; ks < 2; ks++)
            #pragma unroll
            for (int iq = 0; iq < 2; iq++)
                #pragma unroll
                for (int ti = 0; ti < 4; ti++)
                    acc[qd*2+iq][ti] = __builtin_amdgcn_mfma_f32_16x16x32_bf16(
                        af[iq][ks], bfr[ti][ks], acc[qd*2+iq][ti], 0,0,0);
    };

    auto tile = [&](int t, int p) {
        const bool st = (t + 1 < NKT);
        const int kn = (t + 1) << 6;
        bf16x8 af[2][2];

        // ---- phase 0: stage A(t+1); read all B-frags + A-quad 0
        if (st) issueA(kn, p ^ 1);
        readA(p, 0, af);
        #pragma unroll
        for (int ti = 0; ti < 4; ti++)
            #pragma unroll
            for (int ks = 0; ks < 2; ks++)
                bfr[ti][ks] = *(const bf16x8*)&ldsB[p][brow[ti]*64
                                                       + (((ks*4 + lq) ^ (l16 & 7)) << 3)];
        BARRIER; WAIT_LGKM;
        __builtin_amdgcn_s_setprio(1);
        mfma16(0, af);
        __builtin_amdgcn_s_setprio(0);
        BARRIER;

        // ---- phase 1: stage B(t+1); A-quad 1
        if (st) issueB(kn, p ^ 1);
        readA(p, 1, af);
        BARRIER; WAIT_LGKM;
        __builtin_amdgcn_s_setprio(1);
        mfma16(1, af);
        __builtin_amdgcn_s_setprio(0);
        BARRIER;

        // ---- phase 2: A-quad 2
        readA(p, 2, af);
        BARRIER; WAIT_LGKM;
        __builtin_amdgcn_s_setprio(1);
        mfma16(2, af);
        __builtin_amdgcn_s_setprio(0);
        BARRIER;

        // ---- phase 3: A-quad 3; drain tile t+1 staging (issued 2-3 phases ago)
        readA(p, 3, af);
        if (st) WAIT_VM0;
        BARRIER; WAIT_LGKM;
        __builtin_amdgcn_s_setprio(1);
        mfma16(3, af);
        __builtin_amdgcn_s_setprio(0);
        BARRIER;
    };

    issueA(0, 0); issueB(0, 0);
    WAIT_VM0; BARRIER;
    #pragma unroll 1
    for (int t = 0; t < NKT; t += 2) {
        tile(t, 0);
        tile(t + 1, 1);
    }
}

// ---------------------------------------------------------------- QKV GEMM + bias + RoPE + layout (verified R1)
__launch_bounds__(512, 2)
__global__ void gemm_qkv_rope256(const short* __restrict__ A, const short* __restrict__ Bw,
                                 const float* __restrict__ bq, const float* __restrict__ bk,
                                 const float* __restrict__ bv,
                                 const float* __restrict__ cosb, const float* __restrict__ sinb,
                                 short* __restrict__ qo, short* __restrict__ ko, short* __restrict__ vto)
{
    __shared__ short ldsA[2][256*64];
    __shared__ short ldsB[2][256*64];

    const int id = blockIdx.y * 18 + blockIdx.x;
    const int m0 = (id & 7)  * 256;
    const int n0 = (id >> 3) * 256;

    const int tid  = threadIdx.x;
    const int wave = tid >> 6, lane = tid & 63;
    const int lq   = lane >> 4, l16 = lane & 15;
    const int wr   = wave >> 2, wc = wave & 3;
    const int hb   = wc >> 1,  qq = wc & 1;

    int brow[4];
    #pragma unroll
    for (int ti = 0; ti < 4; ti++)
        brow[ti] = hb*128 + (ti>>1)*64 + qq*32 + (ti&1)*16 + l16;

    f32x4 acc[8][4];
    gemm256_core(A, Bw, m0, n0, brow, acc, ldsA, ldsB);

    if (n0 < KOFF) {               // Q region
        const int h = (n0 >> 7) + hb;
        #pragma unroll
        for (int mi = 0; mi < 8; mi++)
            #pragma unroll
            for (int r = 0; r < 4; r++) {
                const int s = m0 + wr*128 + mi*16 + lq*4 + r;
                const size_t base = ((size_t)h*SEQ + s)*HD;
                #pragma unroll
                for (int pi = 0; pi < 2; pi++) {
                    const int d = qq*32 + pi*16 + l16;          // [0,64)
                    const float c  = cosb[s*HD + d];
                    const float sn = sinb[s*HD + d];
                    const float x0 = acc[mi][pi]  [r] + bq[n0 + hb*128 + d];
                    const float x1 = acc[mi][pi+2][r] + bq[n0 + hb*128 + 64 + d];
                    qo[base + d]      = f2bf((x0*c - x1*sn) * QSCALE);
                    qo[base + d + 64] = f2bf((x1*c + x0*sn) * QSCALE);
                }
            }
    } else if (n0 < VOFF) {        // K region
        const int h = ((n0 - KOFF) >> 7) + hb;
        #pragma unroll
        for (int mi = 0; mi < 8; mi++)
            #pragma unroll
            for (int r = 0; r < 4; r++) {
                const int s = m0 + wr*128 + mi*16 + lq*4 + r;
                const size_t base = ((size_t)h*SEQ + s)*HD;
                #pragma unroll
                for (int pi = 0; pi < 2; pi++) {
                    const int d = qq*32 + pi*16 + l16;
                    const float c  = cosb[s*HD + d];
                    const float sn = sinb[s*HD + d];
                    const float x0 = acc[mi][pi]  [r] + bk[n0 - KOFF + hb*128 + d];
                    const float x1 = acc[mi][pi+2][r] + bk[n0 - KOFF + hb*128 + 64 + d];
                    ko[base + d]      = f2bf(x0*c - x1*sn);
                    ko[base + d + 64] = f2bf(x1*c + x0*sn);
                }
            }
    } else {                       // V region -> transposed vt[h][d][s]
        const int h = ((n0 - VOFF) >> 7) + hb;
        #pragma unroll
        for (int mi = 0; mi < 8; mi++)
            #pragma unroll
            for (int r = 0; r < 4; r++) {
                const int s = m0 + wr*128 + mi*16 + lq*4 + r;
                #pragma unroll
                for (int ti = 0; ti < 4; ti++) {
                    const int d = (ti>>1)*64 + qq*32 + (ti&1)*16 + l16;
                    const float v = acc[mi][ti][r] + bv[n0 - VOFF + hb*128 + d];
                    vto[((size_t)h*HD + d)*SEQ + s] = f2bf(v);
                }
            }
    }
}

// ---------------------------------------------------------------- output GEMM: 256x128 tiles, grid 224 (verified R2)
__launch_bounds__(512, 2)
__global__ void gemm_out256(const short* __restrict__ A, const short* __restrict__ Bw,
                            float* __restrict__ C)
{
    __shared__ short ldsA[2][256*64];
    __shared__ short ldsB[2][128*64];

    const int id = blockIdx.x;                // 224 blocks; 224%8==0 -> bijective
    const int m0 = (id & 7)  * 256;
    const int n0 = (id >> 3) * 128;

    const int tid  = threadIdx.x;
    const int wave = tid >> 6, lane = tid & 63;
    const int lq   = lane >> 4, l16 = lane & 15;
    const int wr   = wave >> 2, wc = wave & 3;
    const int lrow = lane >> 3;
    const int gchk = ((lane & 7) ^ lrow) << 3;

    const short* Ab = &A [(size_t)(m0 + wave*8 + lrow)*HID + gchk];
    const short* Bb = &Bw[(size_t)(n0 + wave*8 + lrow)*HID + gchk];

    auto issueA = [&](int k0, int b) {
        #pragma unroll
        for (int j = 0; j < 4; j++)
            gl_lds16(Ab + (size_t)j*64*HID + k0, &ldsA[b][(j*64 + wave*8)*64]);
    };
    auto issueB = [&](int k0, int b) {
        #pragma unroll
        for (int j = 0; j < 2; j++)
            gl_lds16(Bb + (size_t)j*64*HID + k0, &ldsB[b][(j*64 + wave*8)*64]);
    };

    f32x4 acc[8][2];
    #pragma unroll
    for (int i = 0; i < 8; i++)
        #pragma unroll
        for (int j = 0; j < 2; j++) acc[i][j] = (f32x4){0.f,0.f,0.f,0.f};

    bf16x8 bfr[2][2];

    auto readA = [&](int p, int qd, bf16x8 (&af)[2][2]) {
        #pragma unroll
        for (int iq = 0; iq < 2; iq++)
            #pragma unroll
            for (int ks = 0; ks < 2; ks++)
                af[iq][ks] = *(const bf16x8*)&ldsA[p][(wr*128 + (qd*2+iq)*16 + l16)*64
                                                      + (((ks*4 + lq) ^ (l16 & 7)) << 3)];
    };
    auto mfma8 = [&](int qd, const bf16x8 (&af)[2][2]) {
        #pragma unroll
        for (int ks = 0; ks < 2; ks++)
            #pragma unroll
            for (int iq = 0; iq < 2; iq++)
                #pragma unroll
                for (int ti = 0; ti < 2; ti++)
                    acc[qd*2+iq][ti] = __builtin_amdgcn_mfma_f32_16x16x32_bf16(
                        af[iq][ks], bfr[ti][ks], acc[qd*2+iq][ti], 0,0,0);
    };

    auto tile = [&](int t, int p) {
        const bool st = (t + 1 < NKT);
        const int kn = (t + 1) << 6;
        bf16x8 af[2][2];

        if (st) issueA(kn, p ^ 1);
        readA(p, 0, af);
        #pragma unroll
        for (int ti = 0; ti < 2; ti++)
            #pragma unroll
            for (int ks = 0; ks < 2; ks++)
                bfr[ti][ks] = *(const bf16x8*)&ldsB[p][(wc*32 + ti*16 + l16)*64
                                                       + (((ks*4 + lq) ^ (l16 & 7)) << 3)];
        BARRIER; WAIT_LGKM;
        __builtin_amdgcn_s_setprio(1);
        mfma8(0, af);
        __builtin_amdgcn_s_setprio(0);
        BARRIER;

        if (st) issueB(kn, p ^ 1);
        readA(p, 1, af);
        BARRIER; WAIT_LGKM;
        __builtin_amdgcn_s_setprio(1);
        mfma8(1, af);
        __builtin_amdgcn_s_setprio(0);
        BARRIER;

        readA(p, 2, af);
        BARRIER; WAIT_LGKM;
        __builtin_amdgcn_s_setprio(1);
        mfma8(2, af);
        __builtin_amdgcn_s_setprio(0);
        BARRIER;

        readA(p, 3, af);
        if (st) WAIT_VM0;
        BARRIER; WAIT_LGKM;
        __builtin_amdgcn_s_setprio(1);
        mfma8(3, af);
        __builtin_amdgcn_s_setprio(0);
        BARRIER;
    };

    issueA(0, 0); issueB(0, 0);
    WAIT_VM0; BARRIER;
    #pragma unroll 1
    for (int t = 0; t < NKT; t += 2) {
        tile(t, 0);
        tile(t + 1, 1);
    }

    #pragma unroll
    for (int mi = 0; mi < 8; mi++)
        #pragma unroll
        for (int r = 0; r < 4; r++) {
            const int s = m0 + wr*128 + mi*16 + lq*4 + r;
            #pragma unroll
            for (int ti = 0; ti < 2; ti++)
                C[(size_t)s*HID + n0 + wc*32 + ti*16 + l16] = acc[mi][ti][r];
        }
}

// ---------------------------------------------------------------- flash attention
// R6: R5 structure + LDS bank-conflict fix + 4 blocks/CU.
// kbuf/vbuf/pbuf get the GEMM's XOR chunk swizzle (chunk ^= row&7, identical
// on write and read -- legal because attn reg-stages, no global_load_lds).
// Old KP=136 stride: 68 dw % 32 = 4 -> 8-lanes-per-bank-group on BOTH the
// staging ds_writes and the b128 fragment reads (the 3.9M conflicts). Swizzle
// replaces padding: kbuf 64x128 (16K) + vbuf 128x64 (16K) + pbuf 4x16x64 (8K)
// = 40960 B exactly -> 4 blocks/CU (16 waves). __launch_bounds__(256,4) caps
// VGPR at 128. All 896 blocks co-resident -> no dispatch imbalance, 2x TLP.
__launch_bounds__(256, 4)
__global__ void attn_kernel(const short* __restrict__ q, const short* __restrict__ k,
                            const short* __restrict__ vt, short* __restrict__ out)
{
    const int b   = blockIdx.x;            // 896 = 28 heads x 32 sub-tiles
    const int h   = b % NH;
    const int s   = 31 - b / NH;           // heavy sub-tiles dispatched first
    const int q0  = s * 64;
    const int nch = s + 1;
    const int hkv = h / 7;

    const int tid = threadIdx.x;
    const int wave = tid >> 6, lane = tid & 63;
    const int lq = lane >> 4, l16 = lane & 15;

    const short* Q  = q  + (size_t)h   * SEQ * HD;
    const short* Kp = k  + (size_t)hkv * SEQ * HD;
    const short* VT = vt + (size_t)hkv * HD * SEQ;

    __shared__ short kbuf[64*128];         // swizzled, no pad
    __shared__ short vbuf[128*64];
    __shared__ short pbuf[4][16*64];

    const int qr = q0 + wave*16;           // this wave's 16 q-rows

    bf16x8 qf[4];
    #pragma unroll
    for (int ks = 0; ks < 4; ks++)
        qf[ks] = *(const bf16x8*)&Q[(size_t)(qr + l16)*HD + ks*32 + lq*8];

    f32x4 o[8];
    #pragma unroll
    for (int t = 0; t < 8; t++) o[t] = (f32x4){0.f,0.f,0.f,0.f};
    float m_[4] = {-INFINITY,-INFINITY,-INFINITY,-INFINITY};
    float l_[4] = {0.f,0.f,0.f,0.f};

    // register staging (T14): K rows tid>>4 + i*16, V rows tid>>3 + i*32
    const int krow = tid >> 4, kpos = tid & 15;
    const int vd   = tid >> 3, vpos = tid & 7;
    const int kswz = (kpos ^ (krow & 7)) << 3;   // swizzled chunk (const across i*16)
    const int vswz = (vpos ^ (vd & 7)) << 3;
    bf16x8 krg[4], vrg[4];
    auto load_regs = [&](int k0) {
        #pragma unroll
        for (int i = 0; i < 4; i++)
            krg[i] = *(const bf16x8*)&Kp[(size_t)(k0 + krow + i*16)*HD + kpos*8];
        #pragma unroll
        for (int i = 0; i < 4; i++)
            vrg[i] = *(const bf16x8*)&VT[(size_t)(vd + i*32)*SEQ + k0 + vpos*8];
    };
    load_regs(0);

    for (int ci = 0; ci < nch; ci++) {
        const int k0 = ci << 6;
        __syncthreads();                   // prior chunk's kbuf/vbuf reads done
        #pragma unroll
        for (int i = 0; i < 4; i++)
            *(bf16x8*)&kbuf[(krow + i*16)*128 + kswz] = krg[i];
        #pragma unroll
        for (int i = 0; i < 4; i++)
            *(bf16x8*)&vbuf[(vd + i*32)*64 + vswz] = vrg[i];
        if (ci + 1 < nch) load_regs((ci + 1) << 6);   // overlaps whole compute
        __syncthreads();

        // ---- QK^T (one 16-row strip per wave); swizzled kbuf reads
        f32x4 sc[4];
        #pragma unroll
        for (int nt = 0; nt < 4; nt++) sc[nt] = (f32x4){0.f,0.f,0.f,0.f};
        __builtin_amdgcn_s_setprio(1);
        #pragma unroll
        for (int nt = 0; nt < 4; nt++)
            #pragma unroll
            for (int ks = 0; ks < 4; ks++) {
                bf16x8 kf = *(bf16x8*)&kbuf[(nt*16 + l16)*128
                                            + (((ks*4 + lq) ^ (l16 & 7)) << 3)];
                sc[nt] = __builtin_amdgcn_mfma_f32_16x16x32_bf16(qf[ks], kf, sc[nt], 0,0,0);
            }
        __builtin_amdgcn_s_setprio(0);

        if (ci == s) {                     // only the diagonal chunk masks
            #pragma unroll
            for (int nt = 0; nt < 4; nt++) {
                int col = k0 + nt*16 + l16;
                #pragma unroll
                for (int r = 0; r < 4; r++) {
                    int row = qr + lq*4 + r;
                    if (col > row) sc[nt][r] = -INFINITY;
                }
            }
        }

        // ---- online softmax (defer-max, THR=8)
        float mx[4];
        #pragma unroll
        for (int r = 0; r < 4; r++) {
            float v = fmaxf(fmaxf(sc[0][r], sc[1][r]), fmaxf(sc[2][r], sc[3][r]));
            #pragma unroll
            for (int sft = 8; sft >= 1; sft >>= 1) v = fmaxf(v, __shfl_xor(v, sft));
            mx[r] = v;
        }
        bool need = false;
        #pragma unroll
        for (int r = 0; r < 4; r++) need = need || (mx[r] > m_[r] + 8.0f);
        if (__any(need)) {
            float alpha[4];
            #pragma unroll
            for (int r = 0; r < 4; r++) {
                float nm = fmaxf(m_[r], mx[r]);
                alpha[r] = exp2f((m_[r] - nm) * LOG2E);
                m_[r] = nm;
                l_[r] *= alpha[r];
            }
            #pragma unroll
            for (int t = 0; t < 8; t++)
                #pragma unroll
                for (int r = 0; r < 4; r++) o[t][r] *= alpha[r];
        }
        #pragma unroll
        for (int r = 0; r < 4; r++) {
            float sm = 0.f;
            #pragma unroll
            for (int nt = 0; nt < 4; nt++) {
                float p = exp2f((sc[nt][r] - m_[r]) * LOG2E);
                sc[nt][r] = p;
                sm += p;
            }
            #pragma unroll
            for (int sft = 8; sft >= 1; sft >>= 1) sm += __shfl_xor(sm, sft);
            l_[r] += sm;
        }
        // pbuf: swizzled scalar writes; row = lq*4+r, chunk = nt*2 + (l16>>3)
        #pragma unroll
        for (int r = 0; r < 4; r++) {
            const int prow = lq*4 + r;
            #pragma unroll
            for (int nt = 0; nt < 4; nt++) {
                const int chunk = nt*2 + (l16 >> 3);
                pbuf[wave][prow*64 + ((chunk ^ (prow & 7)) << 3) + (l16 & 7)]
                    = f2bf(sc[nt][r]);
            }
        }

        WAIT_LGKM;                         // pbuf is per-wave: no block barrier
        __builtin_amdgcn_sched_barrier(0);

        bf16x8 pf[2];
        #pragma unroll
        for (int kk = 0; kk < 2; kk++)
            pf[kk] = *(bf16x8*)&pbuf[wave][l16*64 + (((kk*4 + lq) ^ (l16 & 7)) << 3)];

        // ---- PV; swizzled vbuf reads
        __builtin_amdgcn_s_setprio(1);
        #pragma unroll
        for (int t = 0; t < 8; t++)
            #pragma unroll
            for (int kk = 0; kk < 2; kk++) {
                bf16x8 vf = *(bf16x8*)&vbuf[(t*16 + l16)*64
                                            + (((kk*4 + lq) ^ (l16 & 7)) << 3)];
                o[t] = __builtin_amdgcn_mfma_f32_16x16x32_bf16(pf[kk], vf, o[t], 0,0,0);
            }
        __builtin_amdgcn_s_setprio(0);
    }

    #pragma unroll
    for (int r = 0; r < 4; r++) {
        float inv = 1.0f / l_[r];
        int srow = qr + lq*4 + r;
        #pragma unroll
        for (int t = 0; t < 8; t++)
            out[(size_t)srow*HID + h*HD + t*16 + l16] = f2bf(o[t][r]*inv);
    }
}

// ---------------------------------------------------------------- launcher
extern "C" void kernel_launch(void* const* d_in, const int* in_sizes, int n_in,
                              void* d_out, int out_size, void* d_ws, size_t ws_size,
                              hipStream_t stream) {
    const float* hidden = (const float*)d_in[0];
    const float* cosb   = (const float*)d_in[1];
    const float* sinb   = (const float*)d_in[2];
    const float* Wq     = (const float*)d_in[3];
    const float* bq     = (const float*)d_in[4];
    const float* Wk     = (const float*)d_in[5];
    const float* bk     = (const float*)d_in[6];
    const float* Wv     = (const float*)d_in[7];
    const float* bv     = (const float*)d_in[8];
    const float* Wo     = (const float*)d_in[9];
    float* out = (float*)d_out;

    char* ws = (char*)d_ws;
    short* hid_bf  = (short*)(ws);                         // 2048*3584*2  = 14,680,064
    short* wqkv_bf = (short*)(ws + 14680064);              // 4608*3584*2  = 33,030,144
    short* wo_bf   = (short*)(ws + 47710208);              // 3584*3584*2  = 25,690,112
    short* q_bf    = (short*)(ws + 73400320);              // 28*2048*128*2= 14,680,064
    short* k_bf    = (short*)(ws + 88080384);              //  4*2048*128*2=  2,097,152
    short* vt_bf   = (short*)(ws + 90177536);              //  4*128*2048*2=  2,097,152
    short* at_bf   = (short*)(ws + 92274688);              // 2048*3584*2  = 14,680,064

    cvt_all<<<dim3((C4+255)/256), dim3(256), 0, stream>>>(hidden, Wq, Wk, Wv, Wo,
                                                          hid_bf, wqkv_bf, wo_bf);

    gemm_qkv_rope256<<<dim3(18,8), dim3(512), 0, stream>>>(hid_bf, wqkv_bf, bq, bk, bv,
                                                           cosb, sinb, q_bf, k_bf, vt_bf);
    attn_kernel<<<dim3(896), dim3(256), 0, stream>>>(q_bf, k_bf, vt_bf, at_bf);
    gemm_out256<<<dim3(224), dim3(512), 0, stream>>>(at_bf, wo_bf, out);
}

// Round 7
// 463.274 us; speedup vs baseline: 1.1949x; 1.1949x over previous
//
#include <hip/hip_runtime.h>
#include <hip/hip_bf16.h>
#include <cmath>
#include <cstdint>

// Problem constants
#define SEQ    2048
#define HID    3584
#define NH     28
#define NKV    4
#define HD     128
#define KOFF   3584
#define VOFF   4096
#define QSCALE 0.08838834764831845f   // 1/sqrt(128)
#define LOG2E  1.4426950408889634f
#define NKT    56                     // K-tiles of 64 over HID=3584

typedef __attribute__((ext_vector_type(8))) short bf16x8;
typedef __attribute__((ext_vector_type(4))) float f32x4;

__device__ inline short f2bf(float f){
    union { float f; uint32_t u; } c; c.f = f;
    uint32_t u = c.u;
    uint32_t r = (u + 0x7fffu + ((u >> 16) & 1u)) >> 16;
    return (short)r;
}

// async global->LDS, 16B per lane; LDS dest = wave-uniform base + lane*16
__device__ __forceinline__ void gl_lds16(const short* g, short* l) {
    __builtin_amdgcn_global_load_lds(
        (const __attribute__((address_space(1))) void*)g,
        (__attribute__((address_space(3))) void*)l,
        16, 0, 0);
}

#define WAIT_VM0  asm volatile("s_waitcnt vmcnt(0)" ::: "memory")
#define WAIT_LGKM asm volatile("s_waitcnt lgkmcnt(0)" ::: "memory")
#define BARRIER   asm volatile("s_barrier" ::: "memory")

// ---------------------------------------------------------------- fused convert (5 segments, compile-time bounds)
#define C0 917504
#define C1 2523136
#define C2 2752512
#define C3 2981888
#define C4 4587520
__global__ void cvt_all(const float* __restrict__ hid, const float* __restrict__ wq,
                        const float* __restrict__ wk,  const float* __restrict__ wv,
                        const float* __restrict__ wo,
                        short* __restrict__ hid_d, short* __restrict__ wqkv_d,
                        short* __restrict__ wo_d)
{
    int i = blockIdx.x * blockDim.x + threadIdx.x;
    if (i >= C4) return;
    const float* src; short* dst; size_t j;
    if      (i < C0) { src = hid; dst = hid_d;                        j = i; }
    else if (i < C1) { src = wq;  dst = wqkv_d;                       j = i - C0; }
    else if (i < C2) { src = wk;  dst = wqkv_d + (size_t)3584*HID;    j = i - C1; }
    else if (i < C3) { src = wv;  dst = wqkv_d + (size_t)4096*HID;    j = i - C2; }
    else             { src = wo;  dst = wo_d;                         j = i - C3; }
    float4 a = ((const float4*)src)[2*j];
    float4 b = ((const float4*)src)[2*j+1];
    bf16x8 o;
    o[0]=f2bf(a.x); o[1]=f2bf(a.y); o[2]=f2bf(a.z); o[3]=f2bf(a.w);
    o[4]=f2bf(b.x); o[5]=f2bf(b.y); o[6]=f2bf(b.z); o[7]=f2bf(b.w);
    ((bf16x8*)dst)[j] = o;
}

// ---------------------------------------------------------------- QKV GEMM: 128x128 tiles, 576 blocks, 2 blocks/CU
// R7: fill fix. 256^2 grid was 144 blocks = 56% CU fill at 1 block/CU; wall =
// T_block regardless of idle CUs. 128^2 x 576 blocks: work/block = T/4, 512
// co-resident (64KB LDS) -> full fill + 2-block-per-CU overlap (one block's
// MFMA covers the other's barrier drains). Same 4-phase counted schedule.
// xcd = id&7 owns M-tile pair -> A-panel L2-resident; all XCDs sweep nt
// together -> B L3-temporal. Wave cols remapped so RoPE pairs stay in-wave.
__launch_bounds__(256, 2)
__global__ void gemm_qkv_rope128(const short* __restrict__ A, const short* __restrict__ Bw,
                                 const float* __restrict__ bq, const float* __restrict__ bk,
                                 const float* __restrict__ bv,
                                 const float* __restrict__ cosb, const float* __restrict__ sinb,
                                 short* __restrict__ qo, short* __restrict__ ko, short* __restrict__ vto)
{
    __shared__ short ldsA[2][128*64];
    __shared__ short ldsB[2][128*64];

    const int id  = blockIdx.x;            // 576 = 16 M-tiles x 36 N-tiles
    const int xcd = id & 7;
    const int j   = id >> 3;               // 0..71
    const int mh  = j >= 36;               // which M-tile of this XCD's pair
    const int nt  = j - (mh ? 36 : 0);
    const int m0  = (xcd*2 + mh) * 128;
    const int n0  = nt * 128;

    const int tid  = threadIdx.x;
    const int wave = tid >> 6, lane = tid & 63;
    const int lq   = lane >> 4, l16 = lane & 15;
    const int wr   = wave >> 1, wc = wave & 1;
    const int lrow = lane >> 3;
    const int gchk = ((lane & 7) ^ lrow) << 3;

    const short* Ab = &A [(size_t)(m0 + wave*8 + lrow)*HID + gchk];
    const short* Bb = &Bw[(size_t)(n0 + wave*8 + lrow)*HID + gchk];

    auto issueA = [&](int k0, int b) {
        #pragma unroll
        for (int jj = 0; jj < 4; jj++)
            gl_lds16(Ab + (size_t)jj*32*HID + k0, &ldsA[b][(jj*32 + wave*8)*64]);
    };
    auto issueB = [&](int k0, int b) {
        #pragma unroll
        for (int jj = 0; jj < 4; jj++)
            gl_lds16(Bb + (size_t)jj*32*HID + k0, &ldsB[b][(jj*32 + wave*8)*64]);
    };

    f32x4 acc[4][4];
    #pragma unroll
    for (int i = 0; i < 4; i++)
        #pragma unroll
        for (int t = 0; t < 4; t++) acc[i][t] = (f32x4){0.f,0.f,0.f,0.f};

    // wave wc owns cols wc*32 + {0..31} and +64 (RoPE pairs in-wave)
    int brow[4];
    #pragma unroll
    for (int ti = 0; ti < 4; ti++)
        brow[ti] = wc*32 + (ti>>1)*64 + (ti&1)*16 + l16;

    bf16x8 bfr[4][2];

    auto readA = [&](int p, int qd, bf16x8 (&af)[2]) {
        #pragma unroll
        for (int ks = 0; ks < 2; ks++)
            af[ks] = *(const bf16x8*)&ldsA[p][(wr*64 + qd*16 + l16)*64
                                              + (((ks*4 + lq) ^ (l16 & 7)) << 3)];
    };
    auto mfma8 = [&](int qd, const bf16x8 (&af)[2]) {
        #pragma unroll
        for (int ks = 0; ks < 2; ks++)
            #pragma unroll
            for (int ti = 0; ti < 4; ti++)
                acc[qd][ti] = __builtin_amdgcn_mfma_f32_16x16x32_bf16(
                    af[ks], bfr[ti][ks], acc[qd][ti], 0,0,0);
    };

    auto tile = [&](int t, int p) {
        const bool st = (t + 1 < NKT);
        const int kn = (t + 1) << 6;
        bf16x8 af[2];

        // phase 0: stage A(t+1); read all B-frags + A-quad 0
        if (st) issueA(kn, p ^ 1);
        readA(p, 0, af);
        #pragma unroll
        for (int ti = 0; ti < 4; ti++)
            #pragma unroll
            for (int ks = 0; ks < 2; ks++)
                bfr[ti][ks] = *(const bf16x8*)&ldsB[p][brow[ti]*64
                                                       + (((ks*4 + lq) ^ (l16 & 7)) << 3)];
        BARRIER; WAIT_LGKM;
        __builtin_amdgcn_s_setprio(1);
        mfma8(0, af);
        __builtin_amdgcn_s_setprio(0);
        BARRIER;

        // phase 1: stage B(t+1); A-quad 1
        if (st) issueB(kn, p ^ 1);
        readA(p, 1, af);
        BARRIER; WAIT_LGKM;
        __builtin_amdgcn_s_setprio(1);
        mfma8(1, af);
        __builtin_amdgcn_s_setprio(0);
        BARRIER;

        // phase 2: A-quad 2
        readA(p, 2, af);
        BARRIER; WAIT_LGKM;
        __builtin_amdgcn_s_setprio(1);
        mfma8(2, af);
        __builtin_amdgcn_s_setprio(0);
        BARRIER;

        // phase 3: A-quad 3; drain staging (issued 2-3 phases ago)
        readA(p, 3, af);
        if (st) WAIT_VM0;
        BARRIER; WAIT_LGKM;
        __builtin_amdgcn_s_setprio(1);
        mfma8(3, af);
        __builtin_amdgcn_s_setprio(0);
        BARRIER;
    };

    issueA(0, 0); issueB(0, 0);
    WAIT_VM0; BARRIER;
    #pragma unroll 1
    for (int t = 0; t < NKT; t += 2) {
        tile(t, 0);
        tile(t + 1, 1);
    }

    if (n0 < KOFF) {               // Q region (one head per tile)
        const int h = n0 >> 7;
        #pragma unroll
        for (int mi = 0; mi < 4; mi++)
            #pragma unroll
            for (int r = 0; r < 4; r++) {
                const int s = m0 + wr*64 + mi*16 + lq*4 + r;
                const size_t base = ((size_t)h*SEQ + s)*HD;
                #pragma unroll
                for (int pi = 0; pi < 2; pi++) {
                    const int d = wc*32 + pi*16 + l16;          // [0,64)
                    const float c  = cosb[s*HD + d];
                    const float sn = sinb[s*HD + d];
                    const float x0 = acc[mi][pi]  [r] + bq[n0 + d];
                    const float x1 = acc[mi][pi+2][r] + bq[n0 + 64 + d];
                    qo[base + d]      = f2bf((x0*c - x1*sn) * QSCALE);
                    qo[base + d + 64] = f2bf((x1*c + x0*sn) * QSCALE);
                }
            }
    } else if (n0 < VOFF) {        // K region
        const int h = (n0 - KOFF) >> 7;
        #pragma unroll
        for (int mi = 0; mi < 4; mi++)
            #pragma unroll
            for (int r = 0; r < 4; r++) {
                const int s = m0 + wr*64 + mi*16 + lq*4 + r;
                const size_t base = ((size_t)h*SEQ + s)*HD;
                #pragma unroll
                for (int pi = 0; pi < 2; pi++) {
                    const int d = wc*32 + pi*16 + l16;
                    const float c  = cosb[s*HD + d];
                    const float sn = sinb[s*HD + d];
                    const float x0 = acc[mi][pi]  [r] + bk[n0 - KOFF + d];
                    const float x1 = acc[mi][pi+2][r] + bk[n0 - KOFF + 64 + d];
                    ko[base + d]      = f2bf(x0*c - x1*sn);
                    ko[base + d + 64] = f2bf(x1*c + x0*sn);
                }
            }
    } else {                       // V region -> transposed vt[h][d][s]
        const int h = (n0 - VOFF) >> 7;
        #pragma unroll
        for (int mi = 0; mi < 4; mi++)
            #pragma unroll
            for (int r = 0; r < 4; r++) {
                const int s = m0 + wr*64 + mi*16 + lq*4 + r;
                #pragma unroll
                for (int ti = 0; ti < 4; ti++) {
                    const int d = (ti>>1)*64 + wc*32 + (ti&1)*16 + l16;
                    const float v = acc[mi][ti][r] + bv[n0 - VOFF + d];
                    vto[((size_t)h*HD + d)*SEQ + s] = f2bf(v);
                }
            }
    }
}

// ---------------------------------------------------------------- output GEMM: 256x128 tiles, grid 224 (verified R2)
__launch_bounds__(512, 2)
__global__ void gemm_out256(const short* __restrict__ A, const short* __restrict__ Bw,
                            float* __restrict__ C)
{
    __shared__ short ldsA[2][256*64];
    __shared__ short ldsB[2][128*64];

    const int id = blockIdx.x;                // 224 blocks; 224%8==0 -> bijective
    const int m0 = (id & 7)  * 256;
    const int n0 = (id >> 3) * 128;

    const int tid  = threadIdx.x;
    const int wave = tid >> 6, lane = tid & 63;
    const int lq   = lane >> 4, l16 = lane & 15;
    const int wr   = wave >> 2, wc = wave & 3;
    const int lrow = lane >> 3;
    const int gchk = ((lane & 7) ^ lrow) << 3;

    const short* Ab = &A [(size_t)(m0 + wave*8 + lrow)*HID + gchk];
    const short* Bb = &Bw[(size_t)(n0 + wave*8 + lrow)*HID + gchk];

    auto issueA = [&](int k0, int b) {
        #pragma unroll
        for (int j = 0; j < 4; j++)
            gl_lds16(Ab + (size_t)j*64*HID + k0, &ldsA[b][(j*64 + wave*8)*64]);
    };
    auto issueB = [&](int k0, int b) {
        #pragma unroll
        for (int j = 0; j < 2; j++)
            gl_lds16(Bb + (size_t)j*64*HID + k0, &ldsB[b][(j*64 + wave*8)*64]);
    };

    f32x4 acc[8][2];
    #pragma unroll
    for (int i = 0; i < 8; i++)
        #pragma unroll
        for (int j = 0; j < 2; j++) acc[i][j] = (f32x4){0.f,0.f,0.f,0.f};

    bf16x8 bfr[2][2];

    auto readA = [&](int p, int qd, bf16x8 (&af)[2][2]) {
        #pragma unroll
        for (int iq = 0; iq < 2; iq++)
            #pragma unroll
            for (int ks = 0; ks < 2; ks++)
                af[iq][ks] = *(const bf16x8*)&ldsA[p][(wr*128 + (qd*2+iq)*16 + l16)*64
                                                      + (((ks*4 + lq) ^ (l16 & 7)) << 3)];
    };
    auto mfma8 = [&](int qd, const bf16x8 (&af)[2][2]) {
        #pragma unroll
        for (int ks = 0; ks < 2; ks++)
            #pragma unroll
            for (int iq = 0; iq < 2; iq++)
                #pragma unroll
                for (int ti = 0; ti < 2; ti++)
                    acc[qd*2+iq][ti] = __builtin_amdgcn_mfma_f32_16x16x32_bf16(
                        af[iq][ks], bfr[ti][ks], acc[qd*2+iq][ti], 0,0,0);
    };

    auto tile = [&](int t, int p) {
        const bool st = (t + 1 < NKT);
        const int kn = (t + 1) << 6;
        bf16x8 af[2][2];

        if (st) issueA(kn, p ^ 1);
        readA(p, 0, af);
        #pragma unroll
        for (int ti = 0; ti < 2; ti++)
            #pragma unroll
            for (int ks = 0; ks < 2; ks++)
                bfr[ti][ks] = *(const bf16x8*)&ldsB[p][(wc*32 + ti*16 + l16)*64
                                                       + (((ks*4 + lq) ^ (l16 & 7)) << 3)];
        BARRIER; WAIT_LGKM;
        __builtin_amdgcn_s_setprio(1);
        mfma8(0, af);
        __builtin_amdgcn_s_setprio(0);
        BARRIER;

        if (st) issueB(kn, p ^ 1);
        readA(p, 1, af);
        BARRIER; WAIT_LGKM;
        __builtin_amdgcn_s_setprio(1);
        mfma8(1, af);
        __builtin_amdgcn_s_setprio(0);
        BARRIER;

        readA(p, 2, af);
        BARRIER; WAIT_LGKM;
        __builtin_amdgcn_s_setprio(1);
        mfma8(2, af);
        __builtin_amdgcn_s_setprio(0);
        BARRIER;

        readA(p, 3, af);
        if (st) WAIT_VM0;
        BARRIER; WAIT_LGKM;
        __builtin_amdgcn_s_setprio(1);
        mfma8(3, af);
        __builtin_amdgcn_s_setprio(0);
        BARRIER;
    };

    issueA(0, 0); issueB(0, 0);
    WAIT_VM0; BARRIER;
    #pragma unroll 1
    for (int t = 0; t < NKT; t += 2) {
        tile(t, 0);
        tile(t + 1, 1);
    }

    #pragma unroll
    for (int mi = 0; mi < 8; mi++)
        #pragma unroll
        for (int r = 0; r < 4; r++) {
            const int s = m0 + wr*128 + mi*16 + lq*4 + r;
            #pragma unroll
            for (int ti = 0; ti < 2; ti++)
                C[(size_t)s*HID + n0 + wc*32 + ti*16 + l16] = acc[mi][ti][r];
        }
}

// ---------------------------------------------------------------- flash attention (exact R5 body, verified)
// R6 lessons: (1) never cap VGPR below need (launch_bounds(256,4) -> 64 VGPR
// -> 80MB scratch spill, 196us); (2) the 3.9M bank conflicts are NOT on the
// attn critical path (R5 <118us with them) -- stop chasing.
#define KP 136
#define VP 72
#define PP 76
__launch_bounds__(256, 2)
__global__ void attn_kernel(const short* __restrict__ q, const short* __restrict__ k,
                            const short* __restrict__ vt, short* __restrict__ out)
{
    const int b   = blockIdx.x;            // 896 = 28 heads x 32 sub-tiles
    const int h   = b % NH;
    const int s   = 31 - b / NH;           // heavy sub-tiles dispatched first
    const int q0  = s * 64;
    const int nch = s + 1;
    const int hkv = h / 7;

    const int tid = threadIdx.x;
    const int wave = tid >> 6, lane = tid & 63;
    const int lq = lane >> 4, l16 = lane & 15;

    const short* Q  = q  + (size_t)h   * SEQ * HD;
    const short* Kp = k  + (size_t)hkv * SEQ * HD;
    const short* VT = vt + (size_t)hkv * HD * SEQ;

    __shared__ short kbuf[64*KP];
    __shared__ short vbuf[128*VP];
    __shared__ short pbuf[4][16*PP];

    const int qr = q0 + wave*16;           // this wave's 16 q-rows

    bf16x8 qf[4];
    #pragma unroll
    for (int ks = 0; ks < 4; ks++)
        qf[ks] = *(const bf16x8*)&Q[(size_t)(qr + l16)*HD + ks*32 + lq*8];

    f32x4 o[8];
    #pragma unroll
    for (int t = 0; t < 8; t++) o[t] = (f32x4){0.f,0.f,0.f,0.f};
    float m_[4] = {-INFINITY,-INFINITY,-INFINITY,-INFINITY};
    float l_[4] = {0.f,0.f,0.f,0.f};

    // register staging (T14): K rows tid>>4 + i*16, V rows tid>>3 + i*32
    const int krow = tid >> 4, kpos = tid & 15;
    const int vd   = tid >> 3, vpos = tid & 7;
    bf16x8 krg[4], vrg[4];
    auto load_regs = [&](int k0) {
        #pragma unroll
        for (int i = 0; i < 4; i++)
            krg[i] = *(const bf16x8*)&Kp[(size_t)(k0 + krow + i*16)*HD + kpos*8];
        #pragma unroll
        for (int i = 0; i < 4; i++)
            vrg[i] = *(const bf16x8*)&VT[(size_t)(vd + i*32)*SEQ + k0 + vpos*8];
    };
    load_regs(0);

    for (int ci = 0; ci < nch; ci++) {
        const int k0 = ci << 6;
        __syncthreads();                   // prior chunk's kbuf/vbuf reads done
        #pragma unroll
        for (int i = 0; i < 4; i++)
            *(bf16x8*)&kbuf[(krow + i*16)*KP + kpos*8] = krg[i];
        #pragma unroll
        for (int i = 0; i < 4; i++)
            *(bf16x8*)&vbuf[(vd + i*32)*VP + vpos*8] = vrg[i];
        if (ci + 1 < nch) load_regs((ci + 1) << 6);   // overlaps whole compute
        __syncthreads();

        // ---- QK^T (one 16-row strip per wave)
        f32x4 sc[4];
        #pragma unroll
        for (int nt = 0; nt < 4; nt++) sc[nt] = (f32x4){0.f,0.f,0.f,0.f};
        __builtin_amdgcn_s_setprio(1);
        #pragma unroll
        for (int nt = 0; nt < 4; nt++)
            #pragma unroll
            for (int ks = 0; ks < 4; ks++) {
                bf16x8 kf = *(bf16x8*)&kbuf[(nt*16 + l16)*KP + ks*32 + lq*8];
                sc[nt] = __builtin_amdgcn_mfma_f32_16x16x32_bf16(qf[ks], kf, sc[nt], 0,0,0);
            }
        __builtin_amdgcn_s_setprio(0);

        if (ci == s) {                     // only the diagonal chunk masks
            #pragma unroll
            for (int nt = 0; nt < 4; nt++) {
                int col = k0 + nt*16 + l16;
                #pragma unroll
                for (int r = 0; r < 4; r++) {
                    int row = qr + lq*4 + r;
                    if (col > row) sc[nt][r] = -INFINITY;
                }
            }
        }

        // ---- online softmax (defer-max, THR=8)
        float mx[4];
        #pragma unroll
        for (int r = 0; r < 4; r++) {
            float v = fmaxf(fmaxf(sc[0][r], sc[1][r]), fmaxf(sc[2][r], sc[3][r]));
            #pragma unroll
            for (int sft = 8; sft >= 1; sft >>= 1) v = fmaxf(v, __shfl_xor(v, sft));
            mx[r] = v;
        }
        bool need = false;
        #pragma unroll
        for (int r = 0; r < 4; r++) need = need || (mx[r] > m_[r] + 8.0f);
        if (__any(need)) {
            float alpha[4];
            #pragma unroll
            for (int r = 0; r < 4; r++) {
                float nm = fmaxf(m_[r], mx[r]);
                alpha[r] = exp2f((m_[r] - nm) * LOG2E);
                m_[r] = nm;
                l_[r] *= alpha[r];
            }
            #pragma unroll
            for (int t = 0; t < 8; t++)
                #pragma unroll
                for (int r = 0; r < 4; r++) o[t][r] *= alpha[r];
        }
        #pragma unroll
        for (int r = 0; r < 4; r++) {
            float sm = 0.f;
            #pragma unroll
            for (int nt = 0; nt < 4; nt++) {
                float p = exp2f((sc[nt][r] - m_[r]) * LOG2E);
                sc[nt][r] = p;
                sm += p;
            }
            #pragma unroll
            for (int sft = 8; sft >= 1; sft >>= 1) sm += __shfl_xor(sm, sft);
            l_[r] += sm;
        }
        #pragma unroll
        for (int r = 0; r < 4; r++)
            #pragma unroll
            for (int nt = 0; nt < 4; nt++)
                pbuf[wave][(lq*4 + r)*PP + nt*16 + l16] = f2bf(sc[nt][r]);

        WAIT_LGKM;                         // pbuf is per-wave: no block barrier
        __builtin_amdgcn_sched_barrier(0);

        bf16x8 pf[2];
        #pragma unroll
        for (int kk = 0; kk < 2; kk++)
            pf[kk] = *(bf16x8*)&pbuf[wave][l16*PP + kk*32 + lq*8];

        // ---- PV
        __builtin_amdgcn_s_setprio(1);
        #pragma unroll
        for (int t = 0; t < 8; t++)
            #pragma unroll
            for (int kk = 0; kk < 2; kk++) {
                bf16x8 vf = *(bf16x8*)&vbuf[(t*16 + l16)*VP + kk*32 + lq*8];
                o[t] = __builtin_amdgcn_mfma_f32_16x16x32_bf16(pf[kk], vf, o[t], 0,0,0);
            }
        __builtin_amdgcn_s_setprio(0);
    }

    #pragma unroll
    for (int r = 0; r < 4; r++) {
        float inv = 1.0f / l_[r];
        int srow = qr + lq*4 + r;
        #pragma unroll
        for (int t = 0; t < 8; t++)
            out[(size_t)srow*HID + h*HD + t*16 + l16] = f2bf(o[t][r]*inv);
    }
}

// ---------------------------------------------------------------- launcher
extern "C" void kernel_launch(void* const* d_in, const int* in_sizes, int n_in,
                              void* d_out, int out_size, void* d_ws, size_t ws_size,
                              hipStream_t stream) {
    const float* hidden = (const float*)d_in[0];
    const float* cosb   = (const float*)d_in[1];
    const float* sinb   = (const float*)d_in[2];
    const float* Wq     = (const float*)d_in[3];
    const float* bq     = (const float*)d_in[4];
    const float* Wk     = (const float*)d_in[5];
    const float* bk     = (const float*)d_in[6];
    const float* Wv     = (const float*)d_in[7];
    const float* bv     = (const float*)d_in[8];
    const float* Wo     = (const float*)d_in[9];
    float* out = (float*)d_out;

    char* ws = (char*)d_ws;
    short* hid_bf  = (short*)(ws);                         // 2048*3584*2  = 14,680,064
    short* wqkv_bf = (short*)(ws + 14680064);              // 4608*3584*2  = 33,030,144
    short* wo_bf   = (short*)(ws + 47710208);              // 3584*3584*2  = 25,690,112
    short* q_bf    = (short*)(ws + 73400320);              // 28*2048*128*2= 14,680,064
    short* k_bf    = (short*)(ws + 88080384);              //  4*2048*128*2=  2,097,152
    short* vt_bf   = (short*)(ws + 90177536);              //  4*128*2048*2=  2,097,152
    short* at_bf   = (short*)(ws + 92274688);              // 2048*3584*2  = 14,680,064

    cvt_all<<<dim3((C4+255)/256), dim3(256), 0, stream>>>(hidden, Wq, Wk, Wv, Wo,
                                                          hid_bf, wqkv_bf, wo_bf);

    gemm_qkv_rope128<<<dim3(576), dim3(256), 0, stream>>>(hid_bf, wqkv_bf, bq, bk, bv,
                                                          cosb, sinb, q_bf, k_bf, vt_bf);
    attn_kernel<<<dim3(896), dim3(256), 0, stream>>>(q_bf, k_bf, vt_bf, at_bf);
    gemm_out256<<<dim3(224), dim3(512), 0, stream>>>(at_bf, wo_bf, out);
}

// Round 8
// 451.635 us; speedup vs baseline: 1.2257x; 1.0258x over previous
//
#include <hip/hip_runtime.h>
#include <hip/hip_bf16.h>
#include <cmath>
#include <cstdint>

// Problem constants
#define SEQ    2048
#define HID    3584
#define NH     28
#define NKV    4
#define HD     128
#define KOFF   3584
#define VOFF   4096
#define QSCALE 0.08838834764831845f   // 1/sqrt(128)
#define LOG2E  1.4426950408889634f
#define NKT    56                     // K-tiles of 64 over HID=3584

typedef __attribute__((ext_vector_type(8))) short bf16x8;
typedef __attribute__((ext_vector_type(4))) float f32x4;

__device__ inline short f2bf(float f){
    union { float f; uint32_t u; } c; c.f = f;
    uint32_t u = c.u;
    uint32_t r = (u + 0x7fffu + ((u >> 16) & 1u)) >> 16;
    return (short)r;
}

// async global->LDS, 16B per lane; LDS dest = wave-uniform base + lane*16
__device__ __forceinline__ void gl_lds16(const short* g, short* l) {
    __builtin_amdgcn_global_load_lds(
        (const __attribute__((address_space(1))) void*)g,
        (__attribute__((address_space(3))) void*)l,
        16, 0, 0);
}

#define WAIT_VM0  asm volatile("s_waitcnt vmcnt(0)" ::: "memory")
#define WAIT_VM2  asm volatile("s_waitcnt vmcnt(2)" ::: "memory")
#define WAIT_VM4  asm volatile("s_waitcnt vmcnt(4)" ::: "memory")
#define WAIT_LGKM asm volatile("s_waitcnt lgkmcnt(0)" ::: "memory")
#define BARRIER   asm volatile("s_barrier" ::: "memory")

// ---------------------------------------------------------------- fused convert (5 segments, compile-time bounds)
#define C0 917504
#define C1 2523136
#define C2 2752512
#define C3 2981888
#define C4 4587520
__global__ void cvt_all(const float* __restrict__ hid, const float* __restrict__ wq,
                        const float* __restrict__ wk,  const float* __restrict__ wv,
                        const float* __restrict__ wo,
                        short* __restrict__ hid_d, short* __restrict__ wqkv_d,
                        short* __restrict__ wo_d)
{
    int i = blockIdx.x * blockDim.x + threadIdx.x;
    if (i >= C4) return;
    const float* src; short* dst; size_t j;
    if      (i < C0) { src = hid; dst = hid_d;                        j = i; }
    else if (i < C1) { src = wq;  dst = wqkv_d;                       j = i - C0; }
    else if (i < C2) { src = wk;  dst = wqkv_d + (size_t)3584*HID;    j = i - C1; }
    else if (i < C3) { src = wv;  dst = wqkv_d + (size_t)4096*HID;    j = i - C2; }
    else             { src = wo;  dst = wo_d;                         j = i - C3; }
    float4 a = ((const float4*)src)[2*j];
    float4 b = ((const float4*)src)[2*j+1];
    bf16x8 o;
    o[0]=f2bf(a.x); o[1]=f2bf(a.y); o[2]=f2bf(a.z); o[3]=f2bf(a.w);
    o[4]=f2bf(b.x); o[5]=f2bf(b.y); o[6]=f2bf(b.z); o[7]=f2bf(b.w);
    ((bf16x8*)dst)[j] = o;
}

// ---------------------------------------------------------------- QKV GEMM + RoPE: 256x256, counted-vmcnt schedule (T4)
// R8: phases = (qm, ks). Per K-tile t, staging of t+1 (into buf p^1) is spread
// as 64-row units: ph0->B{0,1}, ph1->B{2,3}, ph2->A{0,2}, ph3->A{1,3}.
// Consumption: B* and A{0,2} first read at (t+1).ph0; A{1,3} at (t+1).ph2.
// Counted waits (per-wave ledger, loads retire oldest-first):
//   W1 @ ph1 = vmcnt(4): waits A{1,3}(t) [issued (t-1).ph3], leaves B(t+1)x4.
//   W2 @ ph3 = vmcnt(2): waits B(t+1)+A{0,2}(t+1), leaves A{1,3}(t+1)x2.
// vmcnt never drains to 0 in the main loop (the m218 lever). Last tile:
// W1->vmcnt(0), W2 skipped.
__launch_bounds__(512, 2)
__global__ void gemm_qkv_rope256(const short* __restrict__ A, const short* __restrict__ Bw,
                                 const float* __restrict__ bq, const float* __restrict__ bk,
                                 const float* __restrict__ bv,
                                 const float* __restrict__ cosb, const float* __restrict__ sinb,
                                 short* __restrict__ qo, short* __restrict__ ko, short* __restrict__ vto)
{
    __shared__ short ldsA[2][256*64];
    __shared__ short ldsB[2][256*64];

    const int id = blockIdx.y * 18 + blockIdx.x;
    const int m0 = (id & 7)  * 256;
    const int n0 = (id >> 3) * 256;

    const int tid  = threadIdx.x;
    const int wave = tid >> 6, lane = tid & 63;
    const int lq   = lane >> 4, l16 = lane & 15;
    const int wr   = wave >> 2, wc = wave & 3;
    const int hb   = wc >> 1,  qq = wc & 1;
    const int lrow = lane >> 3;
    const int gchk = ((lane & 7) ^ lrow) << 3;

    const short* Ab = &A [(size_t)(m0 + wave*8 + lrow)*HID + gchk];
    const short* Bb = &Bw[(size_t)(n0 + wave*8 + lrow)*HID + gchk];

    auto stA = [&](int k0, int b, int u) {
        gl_lds16(Ab + (size_t)u*64*HID + k0, &ldsA[b][(u*64 + wave*8)*64]);
    };
    auto stB = [&](int k0, int b, int u) {
        gl_lds16(Bb + (size_t)u*64*HID + k0, &ldsB[b][(u*64 + wave*8)*64]);
    };

    f32x4 acc[8][4];
    #pragma unroll
    for (int i = 0; i < 8; i++)
        #pragma unroll
        for (int t = 0; t < 4; t++) acc[i][t] = (f32x4){0.f,0.f,0.f,0.f};

    int brow[4];
    #pragma unroll
    for (int ti = 0; ti < 4; ti++)
        brow[ti] = hb*128 + (ti>>1)*64 + qq*32 + (ti&1)*16 + l16;

    bf16x8 bfr[4][2];

    auto readA4 = [&](int p, int qm, int ks, bf16x8 (&af)[4]) {
        #pragma unroll
        for (int mi = 0; mi < 4; mi++)
            af[mi] = *(const bf16x8*)&ldsA[p][(wr*128 + qm*64 + mi*16 + l16)*64
                                              + (((ks*4 + lq) ^ (l16 & 7)) << 3)];
    };
    auto mfma16 = [&](int qm, int ks, const bf16x8 (&af)[4]) {
        #pragma unroll
        for (int mi = 0; mi < 4; mi++)
            #pragma unroll
            for (int ti = 0; ti < 4; ti++)
                acc[qm*4+mi][ti] = __builtin_amdgcn_mfma_f32_16x16x32_bf16(
                    af[mi], bfr[ti][ks], acc[qm*4+mi][ti], 0,0,0);
    };

    auto tile = [&](int t, int p) {
        const bool st = (t + 1 < NKT);
        const int kn = (t + 1) << 6;
        bf16x8 af[4];

        // ---- phase 0 (qm0,ks0): read all B-frags + A quad; stage B{0,1}(t+1)
        readA4(p, 0, 0, af);
        #pragma unroll
        for (int ti = 0; ti < 4; ti++)
            #pragma unroll
            for (int ks = 0; ks < 2; ks++)
                bfr[ti][ks] = *(const bf16x8*)&ldsB[p][brow[ti]*64
                                                       + (((ks*4 + lq) ^ (l16 & 7)) << 3)];
        if (st) { stB(kn, p^1, 0); stB(kn, p^1, 1); }
        BARRIER; WAIT_LGKM;
        __builtin_amdgcn_s_setprio(1);
        mfma16(0, 0, af);
        __builtin_amdgcn_s_setprio(0);
        BARRIER;

        // ---- phase 1 (qm0,ks1): stage B{2,3}(t+1); W1 for A{1,3}(t)
        readA4(p, 0, 1, af);
        if (st) { stB(kn, p^1, 2); stB(kn, p^1, 3); }
        if (st) { WAIT_VM4; } else { WAIT_VM0; }
        BARRIER; WAIT_LGKM;
        __builtin_amdgcn_s_setprio(1);
        mfma16(0, 1, af);
        __builtin_amdgcn_s_setprio(0);
        BARRIER;

        // ---- phase 2 (qm1,ks0): stage A{0,2}(t+1)
        readA4(p, 1, 0, af);
        if (st) { stA(kn, p^1, 0); stA(kn, p^1, 2); }
        BARRIER; WAIT_LGKM;
        __builtin_amdgcn_s_setprio(1);
        mfma16(1, 0, af);
        __builtin_amdgcn_s_setprio(0);
        BARRIER;

        // ---- phase 3 (qm1,ks1): stage A{1,3}(t+1); W2 counted (leaves A{1,3})
        readA4(p, 1, 1, af);
        if (st) { stA(kn, p^1, 1); stA(kn, p^1, 3); }
        if (st) { WAIT_VM2; }
        BARRIER; WAIT_LGKM;
        __builtin_amdgcn_s_setprio(1);
        mfma16(1, 1, af);
        __builtin_amdgcn_s_setprio(0);
        BARRIER;
    };

    // prologue: tile 0, issue in consume-order; wait leaves A{1,3}(0) in flight
    stB(0,0,0); stB(0,0,1); stB(0,0,2); stB(0,0,3);
    stA(0,0,0); stA(0,0,2); stA(0,0,1); stA(0,0,3);
    WAIT_VM2; BARRIER;
    #pragma unroll 1
    for (int t = 0; t < NKT; t += 2) {
        tile(t, 0);
        tile(t + 1, 1);
    }

    if (n0 < KOFF) {               // Q region
        const int h = (n0 >> 7) + hb;
        #pragma unroll
        for (int mi = 0; mi < 8; mi++)
            #pragma unroll
            for (int r = 0; r < 4; r++) {
                const int s = m0 + wr*128 + mi*16 + lq*4 + r;
                const size_t base = ((size_t)h*SEQ + s)*HD;
                #pragma unroll
                for (int pi = 0; pi < 2; pi++) {
                    const int d = qq*32 + pi*16 + l16;          // [0,64)
                    const float c  = cosb[s*HD + d];
                    const float sn = sinb[s*HD + d];
                    const float x0 = acc[mi][pi]  [r] + bq[n0 + hb*128 + d];
                    const float x1 = acc[mi][pi+2][r] + bq[n0 + hb*128 + 64 + d];
                    qo[base + d]      = f2bf((x0*c - x1*sn) * QSCALE);
                    qo[base + d + 64] = f2bf((x1*c + x0*sn) * QSCALE);
                }
            }
    } else if (n0 < VOFF) {        // K region
        const int h = ((n0 - KOFF) >> 7) + hb;
        #pragma unroll
        for (int mi = 0; mi < 8; mi++)
            #pragma unroll
            for (int r = 0; r < 4; r++) {
                const int s = m0 + wr*128 + mi*16 + lq*4 + r;
                const size_t base = ((size_t)h*SEQ + s)*HD;
                #pragma unroll
                for (int pi = 0; pi < 2; pi++) {
                    const int d = qq*32 + pi*16 + l16;
                    const float c  = cosb[s*HD + d];
                    const float sn = sinb[s*HD + d];
                    const float x0 = acc[mi][pi]  [r] + bk[n0 - KOFF + hb*128 + d];
                    const float x1 = acc[mi][pi+2][r] + bk[n0 - KOFF + hb*128 + 64 + d];
                    ko[base + d]      = f2bf(x0*c - x1*sn);
                    ko[base + d + 64] = f2bf(x1*c + x0*sn);
                }
            }
    } else {                       // V region -> transposed vt[h][d][s]
        const int h = ((n0 - VOFF) >> 7) + hb;
        #pragma unroll
        for (int mi = 0; mi < 8; mi++)
            #pragma unroll
            for (int r = 0; r < 4; r++) {
                const int s = m0 + wr*128 + mi*16 + lq*4 + r;
                #pragma unroll
                for (int ti = 0; ti < 4; ti++) {
                    const int d = (ti>>1)*64 + qq*32 + (ti&1)*16 + l16;
                    const float v = acc[mi][ti][r] + bv[n0 - VOFF + hb*128 + d];
                    vto[((size_t)h*HD + d)*SEQ + s] = f2bf(v);
                }
            }
    }
}

// ---------------------------------------------------------------- output GEMM: 256x128, counted-vmcnt schedule
// Per tile 6 loads/thread: ph0->B{0,1}(t+1), ph2->A{0,2}, ph3->A{1,3}.
// W1 @ ph1 = vmcnt(2) (waits A{1,3}(t), leaves B(t+1)x2);
// W2 @ ph3 = vmcnt(2) (waits B+A{0,2}(t+1), leaves A{1,3}(t+1)x2).
__launch_bounds__(512, 2)
__global__ void gemm_out256(const short* __restrict__ A, const short* __restrict__ Bw,
                            float* __restrict__ C)
{
    __shared__ short ldsA[2][256*64];
    __shared__ short ldsB[2][128*64];

    const int id = blockIdx.x;                // 224 blocks; 224%8==0 -> bijective
    const int m0 = (id & 7)  * 256;
    const int n0 = (id >> 3) * 128;

    const int tid  = threadIdx.x;
    const int wave = tid >> 6, lane = tid & 63;
    const int lq   = lane >> 4, l16 = lane & 15;
    const int wr   = wave >> 2, wc = wave & 3;
    const int lrow = lane >> 3;
    const int gchk = ((lane & 7) ^ lrow) << 3;

    const short* Ab = &A [(size_t)(m0 + wave*8 + lrow)*HID + gchk];
    const short* Bb = &Bw[(size_t)(n0 + wave*8 + lrow)*HID + gchk];

    auto stA = [&](int k0, int b, int u) {
        gl_lds16(Ab + (size_t)u*64*HID + k0, &ldsA[b][(u*64 + wave*8)*64]);
    };
    auto stB = [&](int k0, int b, int u) {
        gl_lds16(Bb + (size_t)u*64*HID + k0, &ldsB[b][(u*64 + wave*8)*64]);
    };

    f32x4 acc[8][2];
    #pragma unroll
    for (int i = 0; i < 8; i++)
        #pragma unroll
        for (int t = 0; t < 2; t++) acc[i][t] = (f32x4){0.f,0.f,0.f,0.f};

    bf16x8 bfr[2][2];

    auto readA4 = [&](int p, int qm, int ks, bf16x8 (&af)[4]) {
        #pragma unroll
        for (int mi = 0; mi < 4; mi++)
            af[mi] = *(const bf16x8*)&ldsA[p][(wr*128 + qm*64 + mi*16 + l16)*64
                                              + (((ks*4 + lq) ^ (l16 & 7)) << 3)];
    };
    auto mfma8 = [&](int qm, int ks, const bf16x8 (&af)[4]) {
        #pragma unroll
        for (int mi = 0; mi < 4; mi++)
            #pragma unroll
            for (int ti = 0; ti < 2; ti++)
                acc[qm*4+mi][ti] = __builtin_amdgcn_mfma_f32_16x16x32_bf16(
                    af[mi], bfr[ti][ks], acc[qm*4+mi][ti], 0,0,0);
    };

    auto tile = [&](int t, int p) {
        const bool st = (t + 1 < NKT);
        const int kn = (t + 1) << 6;
        bf16x8 af[4];

        // phase 0 (qm0,ks0): read B-frags; stage B{0,1}(t+1)
        readA4(p, 0, 0, af);
        #pragma unroll
        for (int ti = 0; ti < 2; ti++)
            #pragma unroll
            for (int ks = 0; ks < 2; ks++)
                bfr[ti][ks] = *(const bf16x8*)&ldsB[p][(wc*32 + ti*16 + l16)*64
                                                       + (((ks*4 + lq) ^ (l16 & 7)) << 3)];
        if (st) { stB(kn, p^1, 0); stB(kn, p^1, 1); }
        BARRIER; WAIT_LGKM;
        __builtin_amdgcn_s_setprio(1);
        mfma8(0, 0, af);
        __builtin_amdgcn_s_setprio(0);
        BARRIER;

        // phase 1 (qm0,ks1): W1 for A{1,3}(t)
        readA4(p, 0, 1, af);
        if (st) { WAIT_VM2; } else { WAIT_VM0; }
        BARRIER; WAIT_LGKM;
        __builtin_amdgcn_s_setprio(1);
        mfma8(0, 1, af);
        __builtin_amdgcn_s_setprio(0);
        BARRIER;

        // phase 2 (qm1,ks0): stage A{0,2}(t+1)
        readA4(p, 1, 0, af);
        if (st) { stA(kn, p^1, 0); stA(kn, p^1, 2); }
        BARRIER; WAIT_LGKM;
        __builtin_amdgcn_s_setprio(1);
        mfma8(1, 0, af);
        __builtin_amdgcn_s_setprio(0);
        BARRIER;

        // phase 3 (qm1,ks1): stage A{1,3}(t+1); W2 counted
        readA4(p, 1, 1, af);
        if (st) { stA(kn, p^1, 1); stA(kn, p^1, 3); }
        if (st) { WAIT_VM2; }
        BARRIER; WAIT_LGKM;
        __builtin_amdgcn_s_setprio(1);
        mfma8(1, 1, af);
        __builtin_amdgcn_s_setprio(0);
        BARRIER;
    };

    // prologue (consume-order): B{0,1}, A{0,2}, A{1,3}; leave A{1,3} in flight
    stB(0,0,0); stB(0,0,1);
    stA(0,0,0); stA(0,0,2); stA(0,0,1); stA(0,0,3);
    WAIT_VM2; BARRIER;
    #pragma unroll 1
    for (int t = 0; t < NKT; t += 2) {
        tile(t, 0);
        tile(t + 1, 1);
    }

    #pragma unroll
    for (int mi = 0; mi < 8; mi++)
        #pragma unroll
        for (int r = 0; r < 4; r++) {
            const int s = m0 + wr*128 + mi*16 + lq*4 + r;
            #pragma unroll
            for (int ti = 0; ti < 2; ti++)
                C[(size_t)s*HID + n0 + wc*32 + ti*16 + l16] = acc[mi][ti][r];
        }
}

// ---------------------------------------------------------------- flash attention (exact R5 body, verified)
#define KP 136
#define VP 72
#define PP 76
__launch_bounds__(256, 2)
__global__ void attn_kernel(const short* __restrict__ q, const short* __restrict__ k,
                            const short* __restrict__ vt, short* __restrict__ out)
{
    const int b   = blockIdx.x;            // 896 = 28 heads x 32 sub-tiles
    const int h   = b % NH;
    const int s   = 31 - b / NH;           // heavy sub-tiles dispatched first
    const int q0  = s * 64;
    const int nch = s + 1;
    const int hkv = h / 7;

    const int tid = threadIdx.x;
    const int wave = tid >> 6, lane = tid & 63;
    const int lq = lane >> 4, l16 = lane & 15;

    const short* Q  = q  + (size_t)h   * SEQ * HD;
    const short* Kp = k  + (size_t)hkv * SEQ * HD;
    const short* VT = vt + (size_t)hkv * HD * SEQ;

    __shared__ short kbuf[64*KP];
    __shared__ short vbuf[128*VP];
    __shared__ short pbuf[4][16*PP];

    const int qr = q0 + wave*16;           // this wave's 16 q-rows

    bf16x8 qf[4];
    #pragma unroll
    for (int ks = 0; ks < 4; ks++)
        qf[ks] = *(const bf16x8*)&Q[(size_t)(qr + l16)*HD + ks*32 + lq*8];

    f32x4 o[8];
    #pragma unroll
    for (int t = 0; t < 8; t++) o[t] = (f32x4){0.f,0.f,0.f,0.f};
    float m_[4] = {-INFINITY,-INFINITY,-INFINITY,-INFINITY};
    float l_[4] = {0.f,0.f,0.f,0.f};

    // register staging (T14): K rows tid>>4 + i*16, V rows tid>>3 + i*32
    const int krow = tid >> 4, kpos = tid & 15;
    const int vd   = tid >> 3, vpos = tid & 7;
    bf16x8 krg[4], vrg[4];
    auto load_regs = [&](int k0) {
        #pragma unroll
        for (int i = 0; i < 4; i++)
            krg[i] = *(const bf16x8*)&Kp[(size_t)(k0 + krow + i*16)*HD + kpos*8];
        #pragma unroll
        for (int i = 0; i < 4; i++)
            vrg[i] = *(const bf16x8*)&VT[(size_t)(vd + i*32)*SEQ + k0 + vpos*8];
    };
    load_regs(0);

    for (int ci = 0; ci < nch; ci++) {
        const int k0 = ci << 6;
        __syncthreads();                   // prior chunk's kbuf/vbuf reads done
        #pragma unroll
        for (int i = 0; i < 4; i++)
            *(bf16x8*)&kbuf[(krow + i*16)*KP + kpos*8] = krg[i];
        #pragma unroll
        for (int i = 0; i < 4; i++)
            *(bf16x8*)&vbuf[(vd + i*32)*VP + vpos*8] = vrg[i];
        if (ci + 1 < nch) load_regs((ci + 1) << 6);   // overlaps whole compute
        __syncthreads();

        // ---- QK^T (one 16-row strip per wave)
        f32x4 sc[4];
        #pragma unroll
        for (int nt = 0; nt < 4; nt++) sc[nt] = (f32x4){0.f,0.f,0.f,0.f};
        __builtin_amdgcn_s_setprio(1);
        #pragma unroll
        for (int nt = 0; nt < 4; nt++)
            #pragma unroll
            for (int ks = 0; ks < 4; ks++) {
                bf16x8 kf = *(bf16x8*)&kbuf[(nt*16 + l16)*KP + ks*32 + lq*8];
                sc[nt] = __builtin_amdgcn_mfma_f32_16x16x32_bf16(qf[ks], kf, sc[nt], 0,0,0);
            }
        __builtin_amdgcn_s_setprio(0);

        if (ci == s) {                     // only the diagonal chunk masks
            #pragma unroll
            for (int nt = 0; nt < 4; nt++) {
                int col = k0 + nt*16 + l16;
                #pragma unroll
                for (int r = 0; r < 4; r++) {
                    int row = qr + lq*4 + r;
                    if (col > row) sc[nt][r] = -INFINITY;
                }
            }
        }

        // ---- online softmax (defer-max, THR=8)
        float mx[4];
        #pragma unroll
        for (int r = 0; r < 4; r++) {
            float v = fmaxf(fmaxf(sc[0][r], sc[1][r]), fmaxf(sc[2][r], sc[3][r]));
            #pragma unroll
            for (int sft = 8; sft >= 1; sft >>= 1) v = fmaxf(v, __shfl_xor(v, sft));
            mx[r] = v;
        }
        bool need = false;
        #pragma unroll
        for (int r = 0; r < 4; r++) need = need || (mx[r] > m_[r] + 8.0f);
        if (__any(need)) {
            float alpha[4];
            #pragma unroll
            for (int r = 0; r < 4; r++) {
                float nm = fmaxf(m_[r], mx[r]);
                alpha[r] = exp2f((m_[r] - nm) * LOG2E);
                m_[r] = nm;
                l_[r] *= alpha[r];
            }
            #pragma unroll
            for (int t = 0; t < 8; t++)
                #pragma unroll
                for (int r = 0; r < 4; r++) o[t][r] *= alpha[r];
        }
        #pragma unroll
        for (int r = 0; r < 4; r++) {
            float sm = 0.f;
            #pragma unroll
            for (int nt = 0; nt < 4; nt++) {
                float p = exp2f((sc[nt][r] - m_[r]) * LOG2E);
                sc[nt][r] = p;
                sm += p;
            }
            #pragma unroll
            for (int sft = 8; sft >= 1; sft >>= 1) sm += __shfl_xor(sm, sft);
            l_[r] += sm;
        }
        #pragma unroll
        for (int r = 0; r < 4; r++)
            #pragma unroll
            for (int nt = 0; nt < 4; nt++)
                pbuf[wave][(lq*4 + r)*PP + nt*16 + l16] = f2bf(sc[nt][r]);

        WAIT_LGKM;                         // pbuf is per-wave: no block barrier
        __builtin_amdgcn_sched_barrier(0);

        bf16x8 pf[2];
        #pragma unroll
        for (int kk = 0; kk < 2; kk++)
            pf[kk] = *(bf16x8*)&pbuf[wave][l16*PP + kk*32 + lq*8];

        // ---- PV
        __builtin_amdgcn_s_setprio(1);
        #pragma unroll
        for (int t = 0; t < 8; t++)
            #pragma unroll
            for (int kk = 0; kk < 2; kk++) {
                bf16x8 vf = *(bf16x8*)&vbuf[(t*16 + l16)*VP + kk*32 + lq*8];
                o[t] = __builtin_amdgcn_mfma_f32_16x16x32_bf16(pf[kk], vf, o[t], 0,0,0);
            }
        __builtin_amdgcn_s_setprio(0);
    }

    #pragma unroll
    for (int r = 0; r < 4; r++) {
        float inv = 1.0f / l_[r];
        int srow = qr + lq*4 + r;
        #pragma unroll
        for (int t = 0; t < 8; t++)
            out[(size_t)srow*HID + h*HD + t*16 + l16] = f2bf(o[t][r]*inv);
    }
}

// ---------------------------------------------------------------- launcher
extern "C" void kernel_launch(void* const* d_in, const int* in_sizes, int n_in,
                              void* d_out, int out_size, void* d_ws, size_t ws_size,
                              hipStream_t stream) {
    const float* hidden = (const float*)d_in[0];
    const float* cosb   = (const float*)d_in[1];
    const float* sinb   = (const float*)d_in[2];
    const float* Wq     = (const float*)d_in[3];
    const float* bq     = (const float*)d_in[4];
    const float* Wk     = (const float*)d_in[5];
    const float* bk     = (const float*)d_in[6];
    const float* Wv     = (const float*)d_in[7];
    const float* bv     = (const float*)d_in[8];
    const float* Wo     = (const float*)d_in[9];
    float* out = (float*)d_out;

    char* ws = (char*)d_ws;
    short* hid_bf  = (short*)(ws);                         // 2048*3584*2  = 14,680,064
    short* wqkv_bf = (short*)(ws + 14680064);              // 4608*3584*2  = 33,030,144
    short* wo_bf   = (short*)(ws + 47710208);              // 3584*3584*2  = 25,690,112
    short* q_bf    = (short*)(ws + 73400320);              // 28*2048*128*2= 14,680,064
    short* k_bf    = (short*)(ws + 88080384);              //  4*2048*128*2=  2,097,152
    short* vt_bf   = (short*)(ws + 90177536);              //  4*128*2048*2=  2,097,152
    short* at_bf   = (short*)(ws + 92274688);              // 2048*3584*2  = 14,680,064

    cvt_all<<<dim3((C4+255)/256), dim3(256), 0, stream>>>(hidden, Wq, Wk, Wv, Wo,
                                                          hid_bf, wqkv_bf, wo_bf);

    gemm_qkv_rope256<<<dim3(18,8), dim3(512), 0, stream>>>(hid_bf, wqkv_bf, bq, bk, bv,
                                                           cosb, sinb, q_bf, k_bf, vt_bf);
    attn_kernel<<<dim3(896), dim3(256), 0, stream>>>(q_bf, k_bf, vt_bf, at_bf);
    gemm_out256<<<dim3(224), dim3(512), 0, stream>>>(at_bf, wo_bf, out);
}